// Round 1
// baseline (266.686 us; speedup 1.0000x reference)
//
#include <hip/hip_runtime.h>

typedef _Float16 f16;
typedef __attribute__((ext_vector_type(8))) _Float16 half8;
typedef __attribute__((ext_vector_type(4))) _Float16 half4;
typedef __attribute__((ext_vector_type(4))) float f32x4;

#define LDS_AS __attribute__((address_space(3)))
#define GLB_AS __attribute__((address_space(1)))

__device__ __forceinline__ void load16_lds(const f16* g, f16* l) {
    __builtin_amdgcn_global_load_lds((GLB_AS void*)(g), (LDS_AS void*)(l), 16, 0, 0);
}

// ---------------------------------------------------------------------------
// MFMA f16 GEMM: C[M][ldc] = A[M][K] * Bt[N][K]^T + bias, 128x128 tile, BK=32
// ---------------------------------------------------------------------------
template <bool HALF_OUT>
__global__ __launch_bounds__(256, 2) void mfma_gemm(
    const f16* __restrict__ A, const f16* __restrict__ Bt,
    const float* __restrict__ bias, int K, int ldc, int bias_valid,
    void* __restrict__ Cout)
{
    __shared__ f16 As[128 * 32];
    __shared__ f16 Bs[128 * 32];
    const int tid  = threadIdx.x;
    const int wave = tid >> 6;
    const int lane = tid & 63;
    const int m0 = blockIdx.y * 128;
    const int n0 = blockIdx.x * 128;

    // staging: 512 16B-segments per tile; seg s -> (row=s>>2, kq=s&3)
    const int s0 = tid, s1 = tid + 256;
    const f16* gA0 = A  + (m0 + (s0 >> 2)) * K + (s0 & 3) * 8;
    const f16* gA1 = A  + (m0 + (s1 >> 2)) * K + (s1 & 3) * 8;
    const f16* gB0 = Bt + (n0 + (s0 >> 2)) * K + (s0 & 3) * 8;
    const f16* gB1 = Bt + (n0 + (s1 >> 2)) * K + (s1 & 3) * 8;
    f16* lA0 = &As[wave * 512];
    f16* lA1 = &As[2048 + wave * 512];
    f16* lB0 = &Bs[wave * 512];
    f16* lB1 = &Bs[2048 + wave * 512];

    const int wm = (wave >> 1) * 64;   // wave 2x2 -> 64x64 each
    const int wn = (wave & 1) * 64;
    const int lr = lane & 15;
    const int k8 = (lane >> 4) * 8;

    f32x4 acc[4][4];
#pragma unroll
    for (int i = 0; i < 4; ++i)
#pragma unroll
        for (int j = 0; j < 4; ++j) acc[i][j] = f32x4{0.f, 0.f, 0.f, 0.f};

    for (int k0 = 0; k0 < K; k0 += 32) {
        load16_lds(gA0 + k0, lA0);
        load16_lds(gA1 + k0, lA1);
        load16_lds(gB0 + k0, lB0);
        load16_lds(gB1 + k0, lB1);
        __syncthreads();
        half8 af[4], bf[4];
#pragma unroll
        for (int i = 0; i < 4; ++i)
            af[i] = *(const half8*)&As[(wm + i * 16 + lr) * 32 + k8];
#pragma unroll
        for (int j = 0; j < 4; ++j)
            bf[j] = *(const half8*)&Bs[(wn + j * 16 + lr) * 32 + k8];
#pragma unroll
        for (int i = 0; i < 4; ++i)
#pragma unroll
            for (int j = 0; j < 4; ++j)
                acc[i][j] = __builtin_amdgcn_mfma_f32_16x16x32_f16(
                    af[i], bf[j], acc[i][j], 0, 0, 0);
        __syncthreads();
    }

    // epilogue: D col = lane&15, row = (lane>>4)*4 + reg
#pragma unroll
    for (int j = 0; j < 4; ++j) {
        const int col = n0 + wn + j * 16 + lr;
        const float bv = (col < bias_valid) ? bias[col] : 0.f;
#pragma unroll
        for (int i = 0; i < 4; ++i) {
            const int rbase = m0 + wm + i * 16 + (lane >> 4) * 4;
#pragma unroll
            for (int r = 0; r < 4; ++r) {
                const float v = acc[i][j][r] + bv;
                if (HALF_OUT)
                    ((f16*)Cout)[(rbase + r) * ldc + col] = (f16)v;
                else
                    ((float*)Cout)[(rbase + r) * ldc + col] = v;
            }
        }
    }
}

// ---------------------------------------------------------------------------
// fold (scatter-add rewritten as gather) + overlap-count normalize
// h16: [11520][2048] f16 (cols c*49+k, c<40, k<49 valid)
// imgN: [16][40][66][114] f32, zero outside crop region [3,63)x[3,111)
// ---------------------------------------------------------------------------
__global__ void fold_norm(const f16* __restrict__ h, float* __restrict__ imgN)
{
    const int r  = blockIdx.x;        // 0..65
    const int bc = blockIdx.y;        // bp*40 + cch, 0..639
    const int bp  = bc / 40;
    const int cch = bc % 40;
    const int c = threadIdx.x;
    if (c >= 114) return;
    float outv = 0.f;
    if (r >= 3 && r < 63 && c >= 3 && c < 111) {
        const int qr = r / 3, rm = r % 3;
        const int qc = c / 3, cm = c % 3;
        int kis[3], ohs[3], nr = 0;
        int kjs[3], ows[3], nc = 0;
#pragma unroll
        for (int t = 0; t < 3; ++t) {
            const int ki = rm + 3 * t, oh = qr - t;
            if (ki < 7 && oh >= 0 && oh < 20) { kis[nr] = ki; ohs[nr] = oh; ++nr; }
            const int kj = cm + 3 * t, ow = qc - t;
            if (kj < 7 && ow >= 0 && ow < 36) { kjs[nc] = kj; ows[nc] = ow; ++nc; }
        }
        float sum = 0.f;
        for (int a = 0; a < nr; ++a)
            for (int b = 0; b < nc; ++b) {
                const int token = bp * 720 + ohs[a] * 36 + ows[b];
                sum += (float)h[token * 2048 + cch * 49 + kis[a] * 7 + kjs[b]];
            }
        outv = sum / (float)(nr * nc);
    }
    imgN[(bc * 66 + r) * 114 + c] = outv;
}

// ---------------------------------------------------------------------------
// unfold + exact GELU -> f16, writing zero tail cols [1960,2048)
// ---------------------------------------------------------------------------
__global__ void unfold_gelu(const float* __restrict__ imgN, f16* __restrict__ g16)
{
    const int i = blockIdx.x * 256 + threadIdx.x;  // < 11520*2048
    const int t = i >> 11;
    const int j = i & 2047;
    float v = 0.f;
    if (j < 1960) {
        const int bp = t / 720, l = t % 720;
        const int oh = l / 36, ow = l % 36;
        const int cch = j / 49, kk = j % 49;
        const int ki = kk / 7, kj = kk % 7;
        const float x = imgN[((bp * 40 + cch) * 66 + oh * 3 + ki) * 114 + ow * 3 + kj];
        v = 0.5f * x * (1.f + erff(x * 0.70710678118654752f));
    }
    g16[i] = (f16)v;
}

// ---------------------------------------------------------------------------
// converters
// ---------------------------------------------------------------------------
__global__ void cvt_x(const float* __restrict__ x, f16* __restrict__ xh, int n4)
{
    const int i = blockIdx.x * 256 + threadIdx.x;
    if (i < n4) {
        const float4 v = ((const float4*)x)[i];
        half4 o;
        o[0] = (f16)v.x; o[1] = (f16)v.y; o[2] = (f16)v.z; o[3] = (f16)v.w;
        ((half4*)xh)[i] = o;
    }
}

// dst[c][r] = (r<R && c<C) ? src[r][c] : 0 ; dst is Cp x Rp f16
__global__ void transpose_pad(const float* __restrict__ src, f16* __restrict__ dst,
                              int R, int C, int Rp, int Cp)
{
    __shared__ float tile[32][33];
    const int r0 = blockIdx.x * 32, c0 = blockIdx.y * 32;
    const int tx = threadIdx.x, ty = threadIdx.y;  // (32,8)
#pragma unroll
    for (int i = 0; i < 32; i += 8) {
        const int r = r0 + ty + i, c = c0 + tx;
        tile[ty + i][tx] = (r < R && c < C) ? src[r * C + c] : 0.f;
    }
    __syncthreads();
#pragma unroll
    for (int i = 0; i < 32; i += 8) {
        const int c = c0 + ty + i, r = r0 + tx;
        if (c < Cp && r < Rp) dst[c * Rp + r] = (f16)tile[tx][ty + i];
    }
}

// ---------------------------------------------------------------------------
extern "C" void kernel_launch(void* const* d_in, const int* in_sizes, int n_in,
                              void* d_out, int out_size, void* d_ws, size_t ws_size,
                              hipStream_t stream)
{
    const float* x  = (const float*)d_in[0];
    const float* W1 = (const float*)d_in[1];
    const float* b1 = (const float*)d_in[2];
    const float* W2 = (const float*)d_in[3];
    const float* b2 = (const float*)d_in[4];

    char* ws = (char*)d_ws;
    f16*   xh   = (f16*)(ws);                                    // 11,796,480 B
    f16*   W1t  = (f16*)(ws + 11796480);                         //  2,097,152 B
    f16*   W2t  = (f16*)(ws + 11796480 + 2097152);               //  2,097,152 B
    f16*   hbuf = (f16*)(ws + 11796480 + 2 * 2097152);           // 47,185,920 B (h16, then g16)
    float* imgN = (float*)(ws + 11796480 + 2 * 2097152 + 47185920); // 19,261,440 B

    // x (11520x512 f32) -> f16
    cvt_x<<<dim3(5760), dim3(256), 0, stream>>>(x, xh, 1474560);
    // W1 (512x1960) -> W1t (2048x512) f16, zero-padded cols
    transpose_pad<<<dim3(16, 64), dim3(32, 8), 0, stream>>>(W1, W1t, 512, 1960, 512, 2048);
    // W2 (1960x512) -> W2t (512x2048) f16, zero-padded K tail
    transpose_pad<<<dim3(64, 16), dim3(32, 8), 0, stream>>>(W2, W2t, 1960, 512, 2048, 512);
    // GEMM1: h16[11520][2048] = xh @ W1t^T + b1
    mfma_gemm<true><<<dim3(16, 90), dim3(256), 0, stream>>>(xh, W1t, b1, 512, 2048, 1960, hbuf);
    // fold + normalize
    fold_norm<<<dim3(66, 640), dim3(128), 0, stream>>>(hbuf, imgN);
    // unfold + GELU (overwrites hbuf as g16; writes zero tail)
    unfold_gelu<<<dim3(92160), dim3(256), 0, stream>>>(imgN, hbuf);
    // GEMM2: out[11520][512] = g16 @ W2t^T + b2
    mfma_gemm<false><<<dim3(4, 90), dim3(256), 0, stream>>>(hbuf, W2t, b2, 2048, 512, 512, (float*)d_out);
}

// Round 2
// 263.572 us; speedup vs baseline: 1.0118x; 1.0118x over previous
//
#include <hip/hip_runtime.h>

typedef _Float16 f16;
typedef __attribute__((ext_vector_type(8))) _Float16 half8;
typedef __attribute__((ext_vector_type(4))) _Float16 half4;
typedef __attribute__((ext_vector_type(4))) float f32x4;

#define LDS_AS __attribute__((address_space(3)))
#define GLB_AS __attribute__((address_space(1)))

__device__ __forceinline__ void load16_lds(const f16* g, f16* l) {
    __builtin_amdgcn_global_load_lds((GLB_AS void*)(g), (LDS_AS void*)(l), 16, 0, 0);
}

// ---------------------------------------------------------------------------
// MFMA f16 GEMM, 128x128 tile, BK=32: C[M][ldc] = A[M][K] * Bt[N][K]^T + bias
// BIAS_ROW: bias indexed by output row (for the transposed GEMM1)
// ---------------------------------------------------------------------------
template <bool HALF_OUT, bool BIAS_ROW>
__global__ __launch_bounds__(256, 2) void mfma_gemm(
    const f16* __restrict__ A, const f16* __restrict__ Bt,
    const float* __restrict__ bias, int K, int ldc, int bias_valid,
    void* __restrict__ Cout)
{
    __shared__ f16 As[128 * 32];
    __shared__ f16 Bs[128 * 32];
    const int tid  = threadIdx.x;
    const int wave = tid >> 6;
    const int lane = tid & 63;
    const int m0 = blockIdx.y * 128;
    const int n0 = blockIdx.x * 128;

    const int s0 = tid, s1 = tid + 256;
    const f16* gA0 = A  + (m0 + (s0 >> 2)) * K + (s0 & 3) * 8;
    const f16* gA1 = A  + (m0 + (s1 >> 2)) * K + (s1 & 3) * 8;
    const f16* gB0 = Bt + (n0 + (s0 >> 2)) * K + (s0 & 3) * 8;
    const f16* gB1 = Bt + (n0 + (s1 >> 2)) * K + (s1 & 3) * 8;
    f16* lA0 = &As[wave * 512];
    f16* lA1 = &As[2048 + wave * 512];
    f16* lB0 = &Bs[wave * 512];
    f16* lB1 = &Bs[2048 + wave * 512];

    const int wm = (wave >> 1) * 64;
    const int wn = (wave & 1) * 64;
    const int lr = lane & 15;
    const int k8 = (lane >> 4) * 8;

    f32x4 acc[4][4];
#pragma unroll
    for (int i = 0; i < 4; ++i)
#pragma unroll
        for (int j = 0; j < 4; ++j) acc[i][j] = f32x4{0.f, 0.f, 0.f, 0.f};

    for (int k0 = 0; k0 < K; k0 += 32) {
        load16_lds(gA0 + k0, lA0);
        load16_lds(gA1 + k0, lA1);
        load16_lds(gB0 + k0, lB0);
        load16_lds(gB1 + k0, lB1);
        __syncthreads();
        half8 af[4], bf[4];
#pragma unroll
        for (int i = 0; i < 4; ++i)
            af[i] = *(const half8*)&As[(wm + i * 16 + lr) * 32 + k8];
#pragma unroll
        for (int j = 0; j < 4; ++j)
            bf[j] = *(const half8*)&Bs[(wn + j * 16 + lr) * 32 + k8];
#pragma unroll
        for (int i = 0; i < 4; ++i)
#pragma unroll
            for (int j = 0; j < 4; ++j)
                acc[i][j] = __builtin_amdgcn_mfma_f32_16x16x32_f16(
                    af[i], bf[j], acc[i][j], 0, 0, 0);
        __syncthreads();
    }

    // D: col = lane&15, row = (lane>>4)*4 + reg
#pragma unroll
    for (int i = 0; i < 4; ++i) {
#pragma unroll
        for (int r = 0; r < 4; ++r) {
            const int row = m0 + wm + i * 16 + (lane >> 4) * 4 + r;
            float bvr = 0.f;
            if (BIAS_ROW) bvr = (row < bias_valid) ? bias[row] : 0.f;
#pragma unroll
            for (int j = 0; j < 4; ++j) {
                const int col = n0 + wn + j * 16 + lr;
                float v = acc[i][j][r] + bvr;
                if (!BIAS_ROW) v += (col < bias_valid) ? bias[col] : 0.f;
                if (HALF_OUT)
                    ((f16*)Cout)[row * ldc + col] = (f16)v;
                else
                    ((float*)Cout)[row * ldc + col] = v;
            }
        }
    }
}

// ---------------------------------------------------------------------------
// GEMM2: 128x64 tile (more blocks -> better CU balance at N=512)
// C[11520][512] = A[11520][2048] * Bt[512][2048]^T + bias(col), f32 out
// ---------------------------------------------------------------------------
__global__ __launch_bounds__(256, 2) void mfma_gemm_n64(
    const f16* __restrict__ A, const f16* __restrict__ Bt,
    const float* __restrict__ bias, float* __restrict__ Cout)
{
    __shared__ f16 As[128 * 32];
    __shared__ f16 Bs[64 * 32];
    const int tid  = threadIdx.x;
    const int wave = tid >> 6;
    const int lane = tid & 63;
    const int m0 = blockIdx.y * 128;
    const int n0 = blockIdx.x * 64;
    const int K = 2048;

    const f16* gA0 = A  + (m0 + (tid >> 2)) * K + (tid & 3) * 8;
    const f16* gA1 = A  + (m0 + 64 + (tid >> 2)) * K + (tid & 3) * 8;
    const f16* gB0 = Bt + (n0 + (tid >> 2)) * K + (tid & 3) * 8;
    f16* lA0 = &As[wave * 512];
    f16* lA1 = &As[2048 + wave * 512];
    f16* lB0 = &Bs[wave * 512];

    const int wm = wave * 32;         // wave tile 32M x 64N
    const int lr = lane & 15;
    const int k8 = (lane >> 4) * 8;

    f32x4 acc[2][4];
#pragma unroll
    for (int i = 0; i < 2; ++i)
#pragma unroll
        for (int j = 0; j < 4; ++j) acc[i][j] = f32x4{0.f, 0.f, 0.f, 0.f};

    for (int k0 = 0; k0 < K; k0 += 32) {
        load16_lds(gA0 + k0, lA0);
        load16_lds(gA1 + k0, lA1);
        load16_lds(gB0 + k0, lB0);
        __syncthreads();
        half8 af[2], bf[4];
#pragma unroll
        for (int i = 0; i < 2; ++i)
            af[i] = *(const half8*)&As[(wm + i * 16 + lr) * 32 + k8];
#pragma unroll
        for (int j = 0; j < 4; ++j)
            bf[j] = *(const half8*)&Bs[(j * 16 + lr) * 32 + k8];
#pragma unroll
        for (int i = 0; i < 2; ++i)
#pragma unroll
            for (int j = 0; j < 4; ++j)
                acc[i][j] = __builtin_amdgcn_mfma_f32_16x16x32_f16(
                    af[i], bf[j], acc[i][j], 0, 0, 0);
        __syncthreads();
    }

#pragma unroll
    for (int j = 0; j < 4; ++j) {
        const int col = n0 + j * 16 + lr;
        const float bv = bias[col];
#pragma unroll
        for (int i = 0; i < 2; ++i) {
            const int rbase = m0 + wm + i * 16 + (lane >> 4) * 4;
#pragma unroll
            for (int r = 0; r < 4; ++r)
                Cout[(rbase + r) * 512 + col] = acc[i][j][r] + bv;
        }
    }
}

// ---------------------------------------------------------------------------
// fold (gather form) + normalize, reading TRANSPOSED h_t[2048][11520]
// imgN: [16][40][66][114] f32, zero outside crop region [3,63)x[3,111)
// ---------------------------------------------------------------------------
__global__ void fold_norm(const f16* __restrict__ h_t, float* __restrict__ imgN)
{
    const int r  = blockIdx.x;        // 0..65
    const int bc = blockIdx.y;        // bp*40 + cch
    const int bp  = bc / 40;
    const int cch = bc % 40;
    const int c = threadIdx.x;
    if (c >= 114) return;
    float outv = 0.f;
    if (r >= 3 && r < 63 && c >= 3 && c < 111) {
        const int qr = r / 3, rm = r % 3;
        const int qc = c / 3, cm = c % 3;
        int kis[3], ohs[3], nr = 0;
        int kjs[3], ows[3], nc = 0;
#pragma unroll
        for (int t = 0; t < 3; ++t) {
            const int ki = rm + 3 * t, oh = qr - t;
            if (ki < 7 && oh >= 0 && oh < 20) { kis[nr] = ki; ohs[nr] = oh; ++nr; }
            const int kj = cm + 3 * t, ow = qc - t;
            if (kj < 7 && ow >= 0 && ow < 36) { kjs[nc] = kj; ows[nc] = ow; ++nc; }
        }
        float sum = 0.f;
        for (int a = 0; a < nr; ++a)
            for (int b = 0; b < nc; ++b) {
                const int n = cch * 49 + kis[a] * 7 + kjs[b];
                const int token = bp * 720 + ohs[a] * 36 + ows[b];
                sum += (float)h_t[n * 11520 + token];
            }
        outv = sum / (float)(nr * nc);
    }
    imgN[(bc * 66 + r) * 114 + c] = outv;
}

// ---------------------------------------------------------------------------
// unfold + exact GELU -> g16[token][2048], zero tail cols [1960,2048)
// ---------------------------------------------------------------------------
__global__ void unfold_gelu(const float* __restrict__ imgN, f16* __restrict__ g16)
{
    const int i = blockIdx.x * 256 + threadIdx.x;
    const int t = i >> 11;
    const int j = i & 2047;
    float v = 0.f;
    if (j < 1960) {
        const int bp = t / 720, l = t % 720;
        const int oh = l / 36, ow = l % 36;
        const int cch = j / 49, kk = j % 49;
        const int ki = kk / 7, kj = kk % 7;
        const float x = imgN[((bp * 40 + cch) * 66 + oh * 3 + ki) * 114 + ow * 3 + kj];
        v = 0.5f * x * (1.f + erff(x * 0.70710678118654752f));
    }
    g16[i] = (f16)v;
}

// ---------------------------------------------------------------------------
__global__ void cvt_x(const float* __restrict__ x, f16* __restrict__ xh, int n4)
{
    const int i = blockIdx.x * 256 + threadIdx.x;
    if (i < n4) {
        const float4 v = ((const float4*)x)[i];
        half4 o;
        o[0] = (f16)v.x; o[1] = (f16)v.y; o[2] = (f16)v.z; o[3] = (f16)v.w;
        ((half4*)xh)[i] = o;
    }
}

// dst[c][r] = (r<R && c<C) ? src[r][c] : 0 ; dst is Cp x Rp f16
__global__ void transpose_pad(const float* __restrict__ src, f16* __restrict__ dst,
                              int R, int C, int Rp, int Cp)
{
    __shared__ float tile[32][33];
    const int r0 = blockIdx.x * 32, c0 = blockIdx.y * 32;
    const int tx = threadIdx.x, ty = threadIdx.y;  // (32,8)
#pragma unroll
    for (int i = 0; i < 32; i += 8) {
        const int r = r0 + ty + i, c = c0 + tx;
        tile[ty + i][tx] = (r < R && c < C) ? src[r * C + c] : 0.f;
    }
    __syncthreads();
#pragma unroll
    for (int i = 0; i < 32; i += 8) {
        const int c = c0 + ty + i, r = r0 + tx;
        if (c < Cp && r < Rp) dst[c * Rp + r] = (f16)tile[tx][ty + i];
    }
}

// ---------------------------------------------------------------------------
extern "C" void kernel_launch(void* const* d_in, const int* in_sizes, int n_in,
                              void* d_out, int out_size, void* d_ws, size_t ws_size,
                              hipStream_t stream)
{
    const float* x  = (const float*)d_in[0];
    const float* W1 = (const float*)d_in[1];
    const float* b1 = (const float*)d_in[2];
    const float* W2 = (const float*)d_in[3];
    const float* b2 = (const float*)d_in[4];

    char* ws = (char*)d_ws;
    f16*   xh   = (f16*)(ws);                                       // 11,796,480 B
    f16*   W1t  = (f16*)(ws + 11796480);                            //  2,097,152 B
    f16*   W2t  = (f16*)(ws + 11796480 + 2097152);                  //  2,097,152 B
    f16*   hbuf = (f16*)(ws + 11796480 + 2 * 2097152);              // 47,185,920 B (h_t, then g16)
    float* imgN = (float*)(ws + 11796480 + 2 * 2097152 + 47185920); // 19,261,440 B

    // x (11520x512 f32) -> f16
    cvt_x<<<dim3(5760), dim3(256), 0, stream>>>(x, xh, 1474560);
    // W1 (512x1960) -> W1t (2048x512) f16, zero-padded rows
    transpose_pad<<<dim3(16, 64), dim3(32, 8), 0, stream>>>(W1, W1t, 512, 1960, 512, 2048);
    // W2 (1960x512) -> W2t (512x2048) f16, zero-padded K tail
    transpose_pad<<<dim3(64, 16), dim3(32, 8), 0, stream>>>(W2, W2t, 1960, 512, 2048, 512);
    // GEMM1 (swapped operands): h_t[2048][11520] = W1t @ xh^T + b1(row)
    mfma_gemm<true, true><<<dim3(90, 16), dim3(256), 0, stream>>>(
        W1t, xh, b1, 512, 11520, 1960, hbuf);
    // fold + normalize (coalesced gather from h_t)
    fold_norm<<<dim3(66, 640), dim3(128), 0, stream>>>(hbuf, imgN);
    // unfold + GELU -> g16[token][2048] (overwrites hbuf; zero tail)
    unfold_gelu<<<dim3(92160), dim3(256), 0, stream>>>(imgN, hbuf);
    // GEMM2: out[11520][512] = g16 @ W2t^T + b2, 128x64 tiles -> 720 blocks
    mfma_gemm_n64<<<dim3(8, 90), dim3(256), 0, stream>>>(hbuf, W2t, b2, (float*)d_out);
}

// Round 3
// 241.974 us; speedup vs baseline: 1.1021x; 1.0893x over previous
//
#include <hip/hip_runtime.h>

typedef _Float16 f16;
typedef __attribute__((ext_vector_type(8))) _Float16 half8;
typedef __attribute__((ext_vector_type(4))) _Float16 half4;
typedef __attribute__((ext_vector_type(4))) float f32x4;

#define LDS_AS __attribute__((address_space(3)))
#define GLB_AS __attribute__((address_space(1)))

__device__ __forceinline__ void load16_lds(const f16* g, f16* l) {
    __builtin_amdgcn_global_load_lds((GLB_AS void*)(g), (LDS_AS void*)(l), 16, 0, 0);
}

// ---------------------------------------------------------------------------
// GEMM1: h_t[2048][11520] = W1t[2048][512] @ xh[11520][512]^T + b1(row), f16 out
// XCD swizzle: each n-column of xh owned by one XCD (id%8); m fastest within.
// ---------------------------------------------------------------------------
__global__ __launch_bounds__(256, 2) void gemm1(
    const f16* __restrict__ A, const f16* __restrict__ Bt,
    const float* __restrict__ bias, f16* __restrict__ C)
{
    const int id  = blockIdx.x;
    const int xcd = id & 7;
    const int r   = id >> 3;          // 0..191
    const int mt  = r & 15;           // 16 m-tiles, fastest within XCD
    const int nt  = xcd + 8 * (r >> 4);
    if (nt >= 90) return;
    const int m0 = mt * 128, n0 = nt * 128;
    const int K = 512, ldc = 11520;

    __shared__ f16 As[128 * 32];
    __shared__ f16 Bs[128 * 32];
    const int tid  = threadIdx.x;
    const int wave = tid >> 6;
    const int lane = tid & 63;

    const int s0 = tid, s1 = tid + 256;
    const f16* gA0 = A  + (m0 + (s0 >> 2)) * K + (s0 & 3) * 8;
    const f16* gA1 = A  + (m0 + (s1 >> 2)) * K + (s1 & 3) * 8;
    const f16* gB0 = Bt + (n0 + (s0 >> 2)) * K + (s0 & 3) * 8;
    const f16* gB1 = Bt + (n0 + (s1 >> 2)) * K + (s1 & 3) * 8;
    f16* lA0 = &As[wave * 512];
    f16* lA1 = &As[2048 + wave * 512];
    f16* lB0 = &Bs[wave * 512];
    f16* lB1 = &Bs[2048 + wave * 512];

    const int wm = (wave >> 1) * 64;
    const int wn = (wave & 1) * 64;
    const int lr = lane & 15;
    const int k8 = (lane >> 4) * 8;

    f32x4 acc[4][4];
#pragma unroll
    for (int i = 0; i < 4; ++i)
#pragma unroll
        for (int j = 0; j < 4; ++j) acc[i][j] = f32x4{0.f, 0.f, 0.f, 0.f};

    for (int k0 = 0; k0 < K; k0 += 32) {
        load16_lds(gA0 + k0, lA0);
        load16_lds(gA1 + k0, lA1);
        load16_lds(gB0 + k0, lB0);
        load16_lds(gB1 + k0, lB1);
        __syncthreads();
        half8 af[4], bf[4];
#pragma unroll
        for (int i = 0; i < 4; ++i)
            af[i] = *(const half8*)&As[(wm + i * 16 + lr) * 32 + k8];
#pragma unroll
        for (int j = 0; j < 4; ++j)
            bf[j] = *(const half8*)&Bs[(wn + j * 16 + lr) * 32 + k8];
#pragma unroll
        for (int i = 0; i < 4; ++i)
#pragma unroll
            for (int j = 0; j < 4; ++j)
                acc[i][j] = __builtin_amdgcn_mfma_f32_16x16x32_f16(
                    af[i], bf[j], acc[i][j], 0, 0, 0);
        __syncthreads();
    }

#pragma unroll
    for (int i = 0; i < 4; ++i) {
#pragma unroll
        for (int rr = 0; rr < 4; ++rr) {
            const int row = m0 + wm + i * 16 + (lane >> 4) * 4 + rr;
            const float bvr = (row < 1960) ? bias[row] : 0.f;
#pragma unroll
            for (int j = 0; j < 4; ++j) {
                const int col = n0 + wn + j * 16 + lr;
                C[row * ldc + col] = (f16)(acc[i][j][rr] + bvr);
            }
        }
    }
}

// ---------------------------------------------------------------------------
// GEMM2: out[11520][512] = g16[11520][2048] @ W2t[512][2048]^T + b2(col), f32
// XCD swizzle: the 4 n-blocks sharing an A row-tile land on the same XCD.
// ---------------------------------------------------------------------------
__global__ __launch_bounds__(256, 2) void gemm2(
    const f16* __restrict__ A, const f16* __restrict__ Bt,
    const float* __restrict__ bias, float* __restrict__ Cout)
{
    const int id  = blockIdx.x;
    const int xcd = id & 7;
    const int j2  = id >> 3;          // 0..47
    const int nt  = j2 & 3;
    const int mt  = (j2 >> 2) * 8 + xcd;
    if (mt >= 90) return;
    const int m0 = mt * 128, n0 = nt * 128;
    const int K = 2048;

    __shared__ f16 As[128 * 32];
    __shared__ f16 Bs[128 * 32];
    const int tid  = threadIdx.x;
    const int wave = tid >> 6;
    const int lane = tid & 63;

    const int s0 = tid, s1 = tid + 256;
    const f16* gA0 = A  + (m0 + (s0 >> 2)) * K + (s0 & 3) * 8;
    const f16* gA1 = A  + (m0 + (s1 >> 2)) * K + (s1 & 3) * 8;
    const f16* gB0 = Bt + (n0 + (s0 >> 2)) * K + (s0 & 3) * 8;
    const f16* gB1 = Bt + (n0 + (s1 >> 2)) * K + (s1 & 3) * 8;
    f16* lA0 = &As[wave * 512];
    f16* lA1 = &As[2048 + wave * 512];
    f16* lB0 = &Bs[wave * 512];
    f16* lB1 = &Bs[2048 + wave * 512];

    const int wm = (wave >> 1) * 64;
    const int wn = (wave & 1) * 64;
    const int lr = lane & 15;
    const int k8 = (lane >> 4) * 8;

    f32x4 acc[4][4];
#pragma unroll
    for (int i = 0; i < 4; ++i)
#pragma unroll
        for (int j = 0; j < 4; ++j) acc[i][j] = f32x4{0.f, 0.f, 0.f, 0.f};

    for (int k0 = 0; k0 < K; k0 += 32) {
        load16_lds(gA0 + k0, lA0);
        load16_lds(gA1 + k0, lA1);
        load16_lds(gB0 + k0, lB0);
        load16_lds(gB1 + k0, lB1);
        __syncthreads();
        half8 af[4], bf[4];
#pragma unroll
        for (int i = 0; i < 4; ++i)
            af[i] = *(const half8*)&As[(wm + i * 16 + lr) * 32 + k8];
#pragma unroll
        for (int j = 0; j < 4; ++j)
            bf[j] = *(const half8*)&Bs[(wn + j * 16 + lr) * 32 + k8];
#pragma unroll
        for (int i = 0; i < 4; ++i)
#pragma unroll
            for (int j = 0; j < 4; ++j)
                acc[i][j] = __builtin_amdgcn_mfma_f32_16x16x32_f16(
                    af[i], bf[j], acc[i][j], 0, 0, 0);
        __syncthreads();
    }

#pragma unroll
    for (int j = 0; j < 4; ++j) {
        const int col = n0 + wn + j * 16 + lr;
        const float bv = bias[col];
#pragma unroll
        for (int i = 0; i < 4; ++i) {
            const int rbase = m0 + wm + i * 16 + (lane >> 4) * 4;
#pragma unroll
            for (int rr = 0; rr < 4; ++rr)
                Cout[(rbase + rr) * 512 + col] = acc[i][j][rr] + bv;
        }
    }
}

// ---------------------------------------------------------------------------
// fold (gather form) + normalize + exact GELU, h_t[2048][11520] -> imgG f16
// imgG: [640][66][114] f16 (bp*40+cch major), zero outside crop [3,63)x[3,111)
// ---------------------------------------------------------------------------
__global__ void fold_gelu(const f16* __restrict__ h_t, f16* __restrict__ imgG)
{
    const int r  = blockIdx.x;        // 0..65
    const int bc = blockIdx.y;        // bp*40 + cch
    const int bp  = bc / 40;
    const int cch = bc % 40;
    const int c = threadIdx.x;
    if (c >= 114) return;
    float outv = 0.f;
    if (r >= 3 && r < 63 && c >= 3 && c < 111) {
        const int qr = r / 3, rm = r % 3;
        const int qc = c / 3, cm = c % 3;
        int kis[3], ohs[3], nr = 0;
        int kjs[3], ows[3], nc = 0;
#pragma unroll
        for (int t = 0; t < 3; ++t) {
            const int ki = rm + 3 * t, oh = qr - t;
            if (ki < 7 && oh >= 0 && oh < 20) { kis[nr] = ki; ohs[nr] = oh; ++nr; }
            const int kj = cm + 3 * t, ow = qc - t;
            if (kj < 7 && ow >= 0 && ow < 36) { kjs[nc] = kj; ows[nc] = ow; ++nc; }
        }
        float sum = 0.f;
        for (int a = 0; a < nr; ++a)
            for (int b = 0; b < nc; ++b) {
                const int n = cch * 49 + kis[a] * 7 + kjs[b];
                const int token = bp * 720 + ohs[a] * 36 + ows[b];
                sum += (float)h_t[n * 11520 + token];
            }
        const float xv = sum / (float)(nr * nc);
        outv = 0.5f * xv * (1.f + erff(xv * 0.70710678118654752f));
    }
    imgG[(bc * 66 + r) * 114 + c] = (f16)outv;
}

// ---------------------------------------------------------------------------
// unfold: pure f16 gather -> g16[token][2048], zero tail cols [1960,2048)
// ---------------------------------------------------------------------------
__global__ void unfold_g(const f16* __restrict__ imgG, f16* __restrict__ g16)
{
    const int i = blockIdx.x * 256 + threadIdx.x;
    const int t = i >> 11;
    const int j = i & 2047;
    f16 v = (f16)0.f;
    if (j < 1960) {
        const int bp = t / 720, l = t % 720;
        const int oh = l / 36, ow = l % 36;
        const int cch = j / 49, kk = j % 49;
        const int ki = kk / 7, kj = kk % 7;
        v = imgG[((bp * 40 + cch) * 66 + oh * 3 + ki) * 114 + ow * 3 + kj];
    }
    g16[i] = v;
}

// ---------------------------------------------------------------------------
__global__ void cvt_x(const float* __restrict__ x, f16* __restrict__ xh, int n4)
{
    const int i = blockIdx.x * 256 + threadIdx.x;
    if (i < n4) {
        const float4 v = ((const float4*)x)[i];
        half4 o;
        o[0] = (f16)v.x; o[1] = (f16)v.y; o[2] = (f16)v.z; o[3] = (f16)v.w;
        ((half4*)xh)[i] = o;
    }
}

// dst[c][r] = (r<R && c<C) ? src[r][c] : 0 ; dst is Cp x Rp f16
__global__ void transpose_pad(const float* __restrict__ src, f16* __restrict__ dst,
                              int R, int C, int Rp, int Cp)
{
    __shared__ float tile[32][33];
    const int r0 = blockIdx.x * 32, c0 = blockIdx.y * 32;
    const int tx = threadIdx.x, ty = threadIdx.y;  // (32,8)
#pragma unroll
    for (int i = 0; i < 32; i += 8) {
        const int r = r0 + ty + i, c = c0 + tx;
        tile[ty + i][tx] = (r < R && c < C) ? src[r * C + c] : 0.f;
    }
    __syncthreads();
#pragma unroll
    for (int i = 0; i < 32; i += 8) {
        const int c = c0 + ty + i, r = r0 + tx;
        if (c < Cp && r < Rp) dst[c * Rp + r] = (f16)tile[tx][ty + i];
    }
}

// ---------------------------------------------------------------------------
extern "C" void kernel_launch(void* const* d_in, const int* in_sizes, int n_in,
                              void* d_out, int out_size, void* d_ws, size_t ws_size,
                              hipStream_t stream)
{
    const float* x  = (const float*)d_in[0];
    const float* W1 = (const float*)d_in[1];
    const float* b1 = (const float*)d_in[2];
    const float* W2 = (const float*)d_in[3];
    const float* b2 = (const float*)d_in[4];

    char* ws = (char*)d_ws;
    f16* xh   = (f16*)(ws);                                       // 11,796,480 B
    f16* W1t  = (f16*)(ws + 11796480);                            //  2,097,152 B
    f16* W2t  = (f16*)(ws + 11796480 + 2097152);                  //  2,097,152 B
    f16* hbuf = (f16*)(ws + 11796480 + 2 * 2097152);              // 47,185,920 B (h_t, then g16)
    f16* imgG = (f16*)(ws + 11796480 + 2 * 2097152 + 47185920);   //  9,630,720 B

    // x (11520x512 f32) -> f16
    cvt_x<<<dim3(5760), dim3(256), 0, stream>>>(x, xh, 1474560);
    // W1 (512x1960) -> W1t (2048x512) f16, zero-padded rows
    transpose_pad<<<dim3(16, 64), dim3(32, 8), 0, stream>>>(W1, W1t, 512, 1960, 512, 2048);
    // W2 (1960x512) -> W2t (512x2048) f16, zero-padded K tail
    transpose_pad<<<dim3(64, 16), dim3(32, 8), 0, stream>>>(W2, W2t, 1960, 512, 2048, 512);
    // GEMM1 (swapped operands, XCD-swizzled): h_t = W1t @ xh^T + b1(row)
    gemm1<<<dim3(1536), dim3(256), 0, stream>>>(W1t, xh, b1, hbuf);
    // fold + normalize + GELU -> f16 image
    fold_gelu<<<dim3(66, 640), dim3(128), 0, stream>>>(hbuf, imgG);
    // unfold (pure gather) -> g16[token][2048] (overwrites hbuf; zero tail)
    unfold_g<<<dim3(92160), dim3(256), 0, stream>>>(imgG, hbuf);
    // GEMM2 (XCD-swizzled): out = g16 @ W2t^T + b2
    gemm2<<<dim3(384), dim3(256), 0, stream>>>(hbuf, W2t, b2, (float*)d_out);
}